// Round 16
// baseline (210.748 us; speedup 1.0000x reference)
//
#include <hip/hip_runtime.h>

// VQ-VAE VectorQuantizer: B=32, C=D=64, H=W=64, K=512
// d_in[0]: inputs  [32,64,64,64] f32 (NCHW, C = embedding dim)
// d_in[1]: embedding [512,64] f32
// d_out: [loss(1) | out(32*64*64*64) | indices(32*4096)] all read as f32
//
// V18 = V17 with the crash bug fixed: V17's screen wrote PACKED i1|i2<<9
// even for unflagged positions, but the new pure writer reads out_idx as a
// plain index -> OOB emb gather (k up to 2^18) -> memory fault. Fix (R13-
// proven emit): screen writes plain (float)i1 when unflagged; packed only
// when g2/g3 flagged. Contract: by the time vq_write runs, out_idx[p] is a
// plain index for EVERY p (screen: unflagged; vq_full: listed g3; vq_res2:
// g2 + overflow leftovers).
// Structure (V17 theory, untested due to the crash):
//   vq_prep:  e2 + bfrag + zeroing.
//   vq_screen: R14 pt=1 MFMA sweep (59us measured).
//   vq_full:  wave-parallel exact scan per g3 entry (R12-proven).
//   vq_res2:  1t/pos sweep: fl==0 exit (95%); g2 -> depth-2 exact resolve;
//             fl&2 leftover = list-overflow only -> loop-based full scan.
//   vq_write: PURE, 2t/pos (1024 blocks = 16 waves/CU): plain idx read,
//             gather emb half-row, 32 coalesced stores, 32-dim loss
//             partial -> block reduce -> ticket finalize. No branches.
// Correctness: screen diff-error <= ~1e-4 < DELTA=2.5e-4; {i1,i2} cover
// argmin unless g3 escalates; exact path = round-0-proven fmaf/pairwise-8
// ordering; first-min kept. Loss partial order changes only (tolerance-
// proven across all rounds).

#define KCODE 512
#define EMB   64
#define HWSZ  4096
#define NPOS  131072
#define DELTA 2.5e-4f

typedef short short8  __attribute__((ext_vector_type(8)));
typedef float float4v __attribute__((ext_vector_type(4)));

// ws float layout (V18):
//   [0] fullCnt (uint)   [1] writer ticket (uint)   [2..7] pad
//   [8..1031]     writer block partials (1024)
//   [1032..1543]  e2 (numpy rounding, by code)
//   [1544..34311] bfrag short8[32][2][2][64] (128 KB)
//   [34312..]     g3 full-scan list (cap from ws_size, <=1024)

// ---------- numpy-exact helpers ----------
__device__ __forceinline__ float np_sumsq64(const float* a) {
    #pragma clang fp contract(off)
    {
        float r0 = a[0] * a[0], r1 = a[1] * a[1], r2 = a[2] * a[2], r3 = a[3] * a[3];
        float r4 = a[4] * a[4], r5 = a[5] * a[5], r6 = a[6] * a[6], r7 = a[7] * a[7];
        for (int i = 8; i < 64; i += 8) {
            r0 += a[i + 0] * a[i + 0];
            r1 += a[i + 1] * a[i + 1];
            r2 += a[i + 2] * a[i + 2];
            r3 += a[i + 3] * a[i + 3];
            r4 += a[i + 4] * a[i + 4];
            r5 += a[i + 5] * a[i + 5];
            r6 += a[i + 6] * a[i + 6];
            r7 += a[i + 7] * a[i + 7];
        }
        return ((r0 + r1) + (r2 + r3)) + ((r4 + r5) + (r6 + r7));
    }
}

// exact numpy distance: u = fl(fl(x2 - 2*xe) + e2k)  (round-0-proven order)
__device__ __forceinline__ float exact_u(const float* x, float x2,
                                         const float* ek, float e2k) {
    float t0 = 0.f, t1 = 0.f, t2 = 0.f, t3 = 0.f;
    #pragma unroll
    for (int c = 0; c < EMB; c += 4) {
        t0 = fmaf(x[c + 0], ek[c + 0], t0);
        t1 = fmaf(x[c + 1], ek[c + 1], t1);
        t2 = fmaf(x[c + 2], ek[c + 2], t2);
        t3 = fmaf(x[c + 3], ek[c + 3], t3);
    }
    float xe  = (t0 + t1) + (t2 + t3);
    float tmp = x2 - 2.0f * xe;     // 2*xe exact -> contraction rounding-identical
    return tmp + e2k;
}

__device__ __forceinline__ unsigned short bf16rne(float f) {
    unsigned u = __float_as_uint(f);
    unsigned r = (u + 0x7FFFu + ((u >> 16) & 1u)) >> 16;
    return (unsigned short)r;
}
__device__ __forceinline__ float bf16tof(unsigned short h) {
    return __uint_as_float((unsigned)h << 16);
}

// sorted-insert of (v,i) into ((M1,I1),(M2,I2),M3); strict < keeps earlier.
#define INS(M1, I1, M2, I2, M3, v, i)                      \
    {                                                      \
        bool lt1 = (v) < (M1), lt2 = (v) < (M2), lt3 = (v) < (M3); \
        (M3) = lt2 ? (M2) : (lt3 ? (v) : (M3));            \
        (I2) = lt1 ? (I1) : (lt2 ? (i) : (I2));            \
        (M2) = lt1 ? (M1) : (lt2 ? (v) : (M2));            \
        (M1) = lt1 ? (v) : (M1);                           \
        (I1) = lt1 ? (i) : (I1);                           \
    }

// ---------- prep: e2 + bfrag + counter zeroing ----------
__global__ void vq_prep(const float* __restrict__ emb, float* __restrict__ ws) {
    int f = blockIdx.x * blockDim.x + threadIdx.x;   // 0..4095
    if (f == 0) { ((unsigned*)ws)[0] = 0u; ((unsigned*)ws)[1] = 0u; }
    if (f < KCODE) ws[1032 + f] = np_sumsq64(emb + f * EMB);
    short8* bfrag = (short8*)(ws + 1544);
    int l = f & 63;
    int c = (f >> 6) & 1;
    int t = f >> 7;            // 0..31
    int code  = t * 16 + (l & 15);
    int dbase = 32 * c + ((l >> 4) & 3) * 8;
    const float* e = emb + code * EMB + dbase;
    short8 h, lo;
    #pragma unroll
    for (int j = 0; j < 8; ++j) {
        float v = e[j];
        unsigned short hb = bf16rne(v);
        float hf = bf16tof(hb);
        unsigned short lb = bf16rne(v - hf);
        h[j]  = (short)hb;
        lo[j] = (short)lb;
    }
    bfrag[t * 256 + c * 128 + 0 * 64 + l] = h;
    bfrag[t * 256 + c * 128 + 1 * 64 + l] = lo;
}

// ---------- screen: pt=1 MFMA sweep, top-3 tracking (R14, 59us) ----------
__global__ __launch_bounds__(256, 4) void vq_screen(
        const float*  __restrict__ in,
        const float*  __restrict__ e2np,      // ws+1032
        const short8* __restrict__ bfrag,     // ws+1544
        float*        __restrict__ out_idx,   // plain i1 OR packed+flags
        unsigned*     __restrict__ fullCnt,   // ws+0
        unsigned*     __restrict__ fullList,  // ws+34312
        int fullCap) {
    const int tid  = threadIdx.x;
    const int wave = tid >> 6;
    const int lane = tid & 63;
    const int lg   = lane >> 4;
    const int lc   = lane & 15;
    const int wavePos = blockIdx.x * 64 + wave * 16;   // 16 positions/wave

    // A-fragments: 1 pos-tile x 2 dim-chunks, hi/lo of g = -2x.
    short8 fH[2], fL[2];
    {
        int pos = wavePos + lc;
        int b   = pos >> 12;
        int hw  = pos & (HWSZ - 1);
        const float* xb = in + ((size_t)b << 18) + hw;
        #pragma unroll
        for (int c = 0; c < 2; ++c) {
            short8 h, lo;
            #pragma unroll
            for (int j = 0; j < 8; ++j) {
                int d = 32 * c + lg * 8 + j;
                float g = -2.0f * xb[(size_t)d << 12];
                unsigned short hb = bf16rne(g);
                float hf = bf16tof(hb);
                unsigned short lb = bf16rne(g - hf);
                h[j]  = (short)hb;
                lo[j] = (short)lb;
            }
            fH[c] = h;
            fL[c] = lo;
        }
    }

    float m1[4], m2[4], m3[4];
    int   i1[4], i2[4];
    #pragma unroll
    for (int r = 0; r < 4; ++r) {
        m1[r] = 3.4e38f; m2[r] = 3.4e38f; m3[r] = 3.4e38f;
        i1[r] = 0;       i2[r] = 0;
    }

    short8 ceh0 = bfrag[lane],       cel0 = bfrag[64 + lane];
    short8 ceh1 = bfrag[128 + lane], cel1 = bfrag[192 + lane];
    float  ce2  = e2np[lc];
    #pragma unroll 2
    for (int t = 0; t < 32; ++t) {
        short8 neh0, nel0, neh1, nel1;
        float  ne2 = 0.0f;
        if (t < 31) {
            const short8* nb = bfrag + (t + 1) * 256;
            neh0 = nb[lane];       nel0 = nb[64 + lane];
            neh1 = nb[128 + lane]; nel1 = nb[192 + lane];
            ne2  = e2np[(t + 1) * 16 + lc];
        }
        const int kf = t * 16 + lc;
        float4v aH = {ce2, ce2, ce2, ce2};
        float4v aM = {0.f, 0.f, 0.f, 0.f};
        float4v aL = {0.f, 0.f, 0.f, 0.f};
        aH = __builtin_amdgcn_mfma_f32_16x16x32_bf16(fH[0], ceh0, aH, 0, 0, 0);
        aM = __builtin_amdgcn_mfma_f32_16x16x32_bf16(fH[0], cel0, aM, 0, 0, 0);
        aL = __builtin_amdgcn_mfma_f32_16x16x32_bf16(fL[0], ceh0, aL, 0, 0, 0);
        aH = __builtin_amdgcn_mfma_f32_16x16x32_bf16(fH[1], ceh1, aH, 0, 0, 0);
        aM = __builtin_amdgcn_mfma_f32_16x16x32_bf16(fH[1], cel1, aM, 0, 0, 0);
        aL = __builtin_amdgcn_mfma_f32_16x16x32_bf16(fL[1], ceh1, aL, 0, 0, 0);
        #pragma unroll
        for (int r = 0; r < 4; ++r) {
            float sv = (aH[r] + aM[r]) + aL[r];
            INS(m1[r], i1[r], m2[r], i2[r], m3[r], sv, kf);
        }
        ceh0 = neh0; cel0 = nel0; ceh1 = neh1; cel1 = nel1; ce2 = ne2;
    }

    // cross-lane top-3 merge over the 16-lane code group
    #pragma unroll
    for (int r = 0; r < 4; ++r) {
        float M1 = m1[r], M2 = m2[r], M3 = m3[r];
        int   I1 = i1[r], I2 = i2[r];
        #pragma unroll
        for (int d = 1; d <= 8; d <<= 1) {
            float pm1 = __shfl_xor(M1, d, 64);
            int   pi1 = __shfl_xor(I1, d, 64);
            float pm2 = __shfl_xor(M2, d, 64);
            int   pi2 = __shfl_xor(I2, d, 64);
            float pm3 = __shfl_xor(M3, d, 64);
            INS(M1, I1, M2, I2, M3, pm1, pi1);
            INS(M1, I1, M2, I2, M3, pm2, pi2);
            M3 = fminf(M3, pm3);    // pm3 >= pm2 >= post-insert M2
        }
        m1[r] = M1; m2[r] = M2; m3[r] = M3;
        i1[r] = I1; i2[r] = I2;
    }

    if (lc == 0) {
        #pragma unroll
        for (int r = 0; r < 4; ++r) {
            int p  = wavePos + lg * 4 + r;
            bool g2 = (m2[r] - m1[r] <= DELTA);
            bool g3 = (m3[r] - m1[r] <= DELTA);
            if (!g2 && !g3) {
                out_idx[p] = (float)i1[r];     // PLAIN: final for the writer
            } else {
                int packed = i1[r] | (i2[r] << 9)
                           | (1 << 18) | (g3 ? (1 << 19) : 0);
                out_idx[p] = (float)packed;    // < 2^20: exact in fp32
                if (g3) {
                    unsigned slot = atomicAdd(fullCnt, 1u);
                    if (slot < (unsigned)fullCap) fullList[slot] = (unsigned)p;
                }
            }
        }
    }
}

// ---------- full-scan: WAVE per listed position, 8 codes/lane (R12) -------
__global__ __launch_bounds__(64) void vq_full(
        const float* __restrict__ in, const float* __restrict__ emb,
        const float* __restrict__ e2np, const unsigned* __restrict__ fullCnt,
        const unsigned* __restrict__ fullList, int fullCap,
        float* __restrict__ out_idx) {
    __shared__ float xbuf[EMB];
    const int lane = threadIdx.x;
    unsigned cnt = *fullCnt;
    if (cnt > (unsigned)fullCap) cnt = (unsigned)fullCap;

    for (unsigned idx = blockIdx.x; idx < cnt; idx += gridDim.x) {
        const int n  = (int)fullList[idx];
        const int b  = n >> 12;
        const int hw = n & (HWSZ - 1);
        xbuf[lane] = in[((size_t)b << 18) + ((size_t)lane << 12) + hw];
        __syncthreads();

        float x2;
        {
            #pragma clang fp contract(off)
            float r0 = xbuf[0] * xbuf[0], r1 = xbuf[1] * xbuf[1];
            float r2 = xbuf[2] * xbuf[2], r3 = xbuf[3] * xbuf[3];
            float r4 = xbuf[4] * xbuf[4], r5 = xbuf[5] * xbuf[5];
            float r6 = xbuf[6] * xbuf[6], r7 = xbuf[7] * xbuf[7];
            #pragma unroll 1
            for (int i = 8; i < EMB; i += 8) {
                r0 += xbuf[i + 0] * xbuf[i + 0];
                r1 += xbuf[i + 1] * xbuf[i + 1];
                r2 += xbuf[i + 2] * xbuf[i + 2];
                r3 += xbuf[i + 3] * xbuf[i + 3];
                r4 += xbuf[i + 4] * xbuf[i + 4];
                r5 += xbuf[i + 5] * xbuf[i + 5];
                r6 += xbuf[i + 6] * xbuf[i + 6];
                r7 += xbuf[i + 7] * xbuf[i + 7];
            }
            x2 = ((r0 + r1) + (r2 + r3)) + ((r4 + r5) + (r6 + r7));
        }

        float bu = 3.4e38f;
        int   bk = 0x7fffffff;
        #pragma unroll 1
        for (int j = 0; j < 8; ++j) {
            const int k = j * 64 + lane;
            const float* ek = emb + (size_t)k * EMB;
            float t0 = 0.f, t1 = 0.f, t2 = 0.f, t3 = 0.f;
            #pragma unroll 4
            for (int c = 0; c < EMB; c += 4) {
                t0 = fmaf(xbuf[c + 0], ek[c + 0], t0);
                t1 = fmaf(xbuf[c + 1], ek[c + 1], t1);
                t2 = fmaf(xbuf[c + 2], ek[c + 2], t2);
                t3 = fmaf(xbuf[c + 3], ek[c + 3], t3);
            }
            float xe  = (t0 + t1) + (t2 + t3);
            float tmp = x2 - 2.0f * xe;
            float u   = tmp + e2np[k];
            if (u < bu || (u == bu && k < bk)) { bu = u; bk = k; }
        }
        #pragma unroll
        for (int d = 1; d < 64; d <<= 1) {
            float ou = __shfl_xor(bu, d, 64);
            int   ok = __shfl_xor(bk, d, 64);
            if (ou < bu || (ou == bu && ok < bk)) { bu = ou; bk = ok; }
        }
        if (lane == 0) out_idx[n] = (float)bk;   // plain index, flags cleared
        __syncthreads();
    }
}

// ---------- res2: 1t/pos sweep, finish ALL remaining resolution ----------
// fl==0 (plain): exit (95%). g2-only: depth-2 exact resolve. fl&2 leftover
// = list overflow only (vq_full ran first): loop-based exact full scan
// (never executed in practice; codegen isolated here, away from writer).
__global__ __launch_bounds__(256) void vq_res2(
        const float* __restrict__ in, const float* __restrict__ emb,
        const float* __restrict__ e2np, float* __restrict__ out_idx) {
    const int n = blockIdx.x * 256 + threadIdx.x;
    const int v = (int)out_idx[n];
    const int fl = v >> 18;
    if (!fl) return;
    const int b  = n >> 12;
    const int hw = n & (HWSZ - 1);
    const float* xp = in + ((size_t)b << 18) + hw;
    float x[EMB];
    #pragma unroll
    for (int c = 0; c < EMB; ++c) x[c] = xp[(size_t)c << 12];
    const float x2 = np_sumsq64(x);
    int kk;
    if (fl & 2) {
        // overflow safety net: exact full scan, first-min semantics
        float bu = 3.4e38f; int bk = 0;
        for (int k = 0; k < KCODE; ++k) {
            float u = exact_u(x, x2, emb + k * EMB, e2np[k]);
            if (u < bu) { bu = u; bk = k; }
        }
        kk = bk;
    } else {
        const int ia = v & 511, ib = (v >> 9) & 511;
        float u1 = exact_u(x, x2, emb + (size_t)ia * EMB, e2np[ia]);
        float u2 = exact_u(x, x2, emb + (size_t)ib * EMB, e2np[ib]);
        kk = (u1 < u2) ? ia : (u2 < u1 ? ib : (ia < ib ? ia : ib));
    }
    out_idx[n] = (float)kk;
}

// ---------- writer: PURE, 2 threads/position (no branches) ----------
__global__ __launch_bounds__(256) void vq_write(
        const float* __restrict__ in, const float* __restrict__ emb,
        const float* __restrict__ out_idx, float* __restrict__ out_q,
        float* __restrict__ partials,           // ws+8, [1024]
        unsigned* __restrict__ ticket,          // ws+1
        float* __restrict__ out_loss) {
    const int tid  = threadIdx.x;
    const int wave = tid >> 6;
    const int lane = tid & 63;
    const int g    = blockIdx.x * 256 + tid;
    const int p    = g >> 1;                 // position
    const int h    = g & 1;                  // dim half (0: d<32, 1: d>=32)
    const int b    = p >> 12;
    const int hw   = p & (HWSZ - 1);

    const int k = (int)out_idx[p];           // plain (screen/full/res2 contract)
    const float4* q4 = (const float4*)(emb + (size_t)k * EMB + h * 32);
    const size_t base = ((size_t)b << 18) + ((size_t)(h * 32) << 12) + hw;
    const float* xp = in    + base;
    float*       op = out_q + base;

    float s = 0.0f;
    #pragma unroll
    for (int c4 = 0; c4 < 8; ++c4) {
        float4 q = q4[c4];
        float a0 = xp[(size_t)(c4 * 4 + 0) << 12];
        float a1 = xp[(size_t)(c4 * 4 + 1) << 12];
        float a2 = xp[(size_t)(c4 * 4 + 2) << 12];
        float a3 = xp[(size_t)(c4 * 4 + 3) << 12];
        float d0 = q.x - a0, d1 = q.y - a1, d2 = q.z - a2, d3 = q.w - a3;
        s = fmaf(d0, d0, s); s = fmaf(d1, d1, s);
        s = fmaf(d2, d2, s); s = fmaf(d3, d3, s);
        op[(size_t)(c4 * 4 + 0) << 12] = q.x;
        op[(size_t)(c4 * 4 + 1) << 12] = q.y;
        op[(size_t)(c4 * 4 + 2) << 12] = q.z;
        op[(size_t)(c4 * 4 + 3) << 12] = q.w;
    }

    // loss: wave shuffle -> LDS -> block partial -> last-block ticket
    #pragma unroll
    for (int off = 32; off > 0; off >>= 1)
        s += __shfl_down(s, off, 64);
    __shared__ float red[4];
    if (lane == 0) red[wave] = s;
    __syncthreads();
    if (tid == 0) {
        partials[blockIdx.x] = (red[0] + red[1]) + (red[2] + red[3]);
        __threadfence();
        unsigned tk = atomicAdd(ticket, 1u);
        if (tk == 1023u) {
            __threadfence();
            float a0 = 0.f, a1 = 0.f, a2 = 0.f, a3 = 0.f;
            float a4 = 0.f, a5 = 0.f, a6 = 0.f, a7 = 0.f;
            for (int i = 0; i < 1024; i += 8) {
                a0 += partials[i + 0]; a1 += partials[i + 1];
                a2 += partials[i + 2]; a3 += partials[i + 3];
                a4 += partials[i + 4]; a5 += partials[i + 5];
                a6 += partials[i + 6]; a7 += partials[i + 7];
            }
            float tot = ((a0 + a1) + (a2 + a3)) + ((a4 + a5) + (a6 + a7));
            out_loss[0] = 1.25f * tot * (1.0f / ((float)NPOS * (float)EMB));
        }
    }
}

extern "C" void kernel_launch(void* const* d_in, const int* in_sizes, int n_in,
                              void* d_out, int out_size, void* d_ws, size_t ws_size,
                              hipStream_t stream) {
    const float* in  = (const float*)d_in[0];
    const float* emb = (const float*)d_in[1];
    float* ws  = (float*)d_ws;
    float* out = (float*)d_out;

    float*    out_loss = out;
    float*    out_q    = out + 1;
    float*    out_idx  = out + 1 + (size_t)NPOS * EMB;
    unsigned* fullCnt  = (unsigned*)ws;          // ws[0]
    unsigned* ticket   = (unsigned*)ws + 1;      // ws[1]
    float*    partials = ws + 8;                 // [1024]
    float*    e2np     = ws + 1032;              // [512]
    short8*   bfrag    = (short8*)(ws + 1544);   // 128 KB
    unsigned* fullList = (unsigned*)(ws + 34312);

    // g3 list capacity limited by what the workspace provably holds;
    // shrinkage only triggers res2's (correct) overflow path.
    long avail = (long)(ws_size / 4) - 34312;
    int  fullCap = avail > 0 ? (avail > 1024 ? 1024 : (int)avail) : 0;

    vq_prep<<<16, 256, 0, stream>>>(emb, ws);
    vq_screen<<<NPOS / 64, 256, 0, stream>>>(in, e2np, bfrag, out_idx,
                                             fullCnt, fullList, fullCap);
    vq_full<<<256, 64, 0, stream>>>(in, emb, e2np, fullCnt, fullList, fullCap,
                                    out_idx);
    vq_res2<<<NPOS / 256, 256, 0, stream>>>(in, emb, e2np, out_idx);
    vq_write<<<NPOS * 2 / 256, 256, 0, stream>>>(in, emb, out_idx, out_q,
                                                 partials, ticket, out_loss);
}

// Round 17
// 183.452 us; speedup vs baseline: 1.1488x; 1.1488x over previous
//
#include <hip/hip_runtime.h>

// VQ-VAE VectorQuantizer: B=32, C=D=64, H=W=64, K=512
// d_in[0]: inputs  [32,64,64,64] f32 (NCHW, C = embedding dim)
// d_in[1]: embedding [512,64] f32
// d_out: [loss(1) | out(32*64*64*64) | indices(32*4096)] all read as f32
//
// V19 = V18 with the writer rebuilt FLOAT4-ALONG-HW.
// V18's 2t/pos writer regressed (57->88us): adjacent lanes alternated
// dim-halves -> every ld/st instruction straddled two 128B planes -> 2
// half-width transactions each. The writer is VMEM-TRANSACTION-limited,
// not TLP-limited. Fix: thread owns 4 consecutive positions x 16 dims;
// out_q[b][d][hw] is hw-contiguous so 4 positions' same-dim values form
// one float4. Per 4-dim group: 4 divergent emb gathers (L2-hot) + 4
// contiguous float4 x loads + register transpose + 4 contiguous float4
// stores. 49 VMEM/thread (vs 145): 6.4M total vs 19M, all full-width.
// quarter = g>>15 so a wave's 64 lanes share the dim-plane -> 1KB/instr.
// Everything else V18 byte-for-byte (R16-passed): pt=1 screen (59us),
// plain/packed emit contract, wave-parallel vq_full, res2 sweep.
// Correctness: screen diff-error <= ~1e-4 < DELTA=2.5e-4; {i1,i2} cover
// argmin unless g3 escalates; exact path = round-0-proven fmaf/pairwise-8
// ordering; first-min kept. Loss partial order changes only (tolerance-
// proven across all rounds).

#define KCODE 512
#define EMB   64
#define HWSZ  4096
#define NPOS  131072
#define DELTA 2.5e-4f

typedef short short8  __attribute__((ext_vector_type(8)));
typedef float float4v __attribute__((ext_vector_type(4)));

// ws float layout (V19):
//   [0] fullCnt (uint)   [1] writer ticket (uint)   [2..7] pad
//   [8..519]      writer block partials (512)
//   [1032..1543]  e2 (numpy rounding, by code)
//   [1544..34311] bfrag short8[32][2][2][64] (128 KB)
//   [34312..]     g3 full-scan list (cap from ws_size, <=1024)

// ---------- numpy-exact helpers ----------
__device__ __forceinline__ float np_sumsq64(const float* a) {
    #pragma clang fp contract(off)
    {
        float r0 = a[0] * a[0], r1 = a[1] * a[1], r2 = a[2] * a[2], r3 = a[3] * a[3];
        float r4 = a[4] * a[4], r5 = a[5] * a[5], r6 = a[6] * a[6], r7 = a[7] * a[7];
        for (int i = 8; i < 64; i += 8) {
            r0 += a[i + 0] * a[i + 0];
            r1 += a[i + 1] * a[i + 1];
            r2 += a[i + 2] * a[i + 2];
            r3 += a[i + 3] * a[i + 3];
            r4 += a[i + 4] * a[i + 4];
            r5 += a[i + 5] * a[i + 5];
            r6 += a[i + 6] * a[i + 6];
            r7 += a[i + 7] * a[i + 7];
        }
        return ((r0 + r1) + (r2 + r3)) + ((r4 + r5) + (r6 + r7));
    }
}

// exact numpy distance: u = fl(fl(x2 - 2*xe) + e2k)  (round-0-proven order)
__device__ __forceinline__ float exact_u(const float* x, float x2,
                                         const float* ek, float e2k) {
    float t0 = 0.f, t1 = 0.f, t2 = 0.f, t3 = 0.f;
    #pragma unroll
    for (int c = 0; c < EMB; c += 4) {
        t0 = fmaf(x[c + 0], ek[c + 0], t0);
        t1 = fmaf(x[c + 1], ek[c + 1], t1);
        t2 = fmaf(x[c + 2], ek[c + 2], t2);
        t3 = fmaf(x[c + 3], ek[c + 3], t3);
    }
    float xe  = (t0 + t1) + (t2 + t3);
    float tmp = x2 - 2.0f * xe;     // 2*xe exact -> contraction rounding-identical
    return tmp + e2k;
}

__device__ __forceinline__ unsigned short bf16rne(float f) {
    unsigned u = __float_as_uint(f);
    unsigned r = (u + 0x7FFFu + ((u >> 16) & 1u)) >> 16;
    return (unsigned short)r;
}
__device__ __forceinline__ float bf16tof(unsigned short h) {
    return __uint_as_float((unsigned)h << 16);
}

// sorted-insert of (v,i) into ((M1,I1),(M2,I2),M3); strict < keeps earlier.
#define INS(M1, I1, M2, I2, M3, v, i)                      \
    {                                                      \
        bool lt1 = (v) < (M1), lt2 = (v) < (M2), lt3 = (v) < (M3); \
        (M3) = lt2 ? (M2) : (lt3 ? (v) : (M3));            \
        (I2) = lt1 ? (I1) : (lt2 ? (i) : (I2));            \
        (M2) = lt1 ? (M1) : (lt2 ? (v) : (M2));            \
        (M1) = lt1 ? (v) : (M1);                           \
        (I1) = lt1 ? (i) : (I1);                           \
    }

// ---------- prep: e2 + bfrag + counter zeroing ----------
__global__ void vq_prep(const float* __restrict__ emb, float* __restrict__ ws) {
    int f = blockIdx.x * blockDim.x + threadIdx.x;   // 0..4095
    if (f == 0) { ((unsigned*)ws)[0] = 0u; ((unsigned*)ws)[1] = 0u; }
    if (f < KCODE) ws[1032 + f] = np_sumsq64(emb + f * EMB);
    short8* bfrag = (short8*)(ws + 1544);
    int l = f & 63;
    int c = (f >> 6) & 1;
    int t = f >> 7;            // 0..31
    int code  = t * 16 + (l & 15);
    int dbase = 32 * c + ((l >> 4) & 3) * 8;
    const float* e = emb + code * EMB + dbase;
    short8 h, lo;
    #pragma unroll
    for (int j = 0; j < 8; ++j) {
        float v = e[j];
        unsigned short hb = bf16rne(v);
        float hf = bf16tof(hb);
        unsigned short lb = bf16rne(v - hf);
        h[j]  = (short)hb;
        lo[j] = (short)lb;
    }
    bfrag[t * 256 + c * 128 + 0 * 64 + l] = h;
    bfrag[t * 256 + c * 128 + 1 * 64 + l] = lo;
}

// ---------- screen: pt=1 MFMA sweep, top-3 tracking (R14, 59us) ----------
__global__ __launch_bounds__(256, 4) void vq_screen(
        const float*  __restrict__ in,
        const float*  __restrict__ e2np,      // ws+1032
        const short8* __restrict__ bfrag,     // ws+1544
        float*        __restrict__ out_idx,   // plain i1 OR packed+flags
        unsigned*     __restrict__ fullCnt,   // ws+0
        unsigned*     __restrict__ fullList,  // ws+34312
        int fullCap) {
    const int tid  = threadIdx.x;
    const int wave = tid >> 6;
    const int lane = tid & 63;
    const int lg   = lane >> 4;
    const int lc   = lane & 15;
    const int wavePos = blockIdx.x * 64 + wave * 16;   // 16 positions/wave

    // A-fragments: 1 pos-tile x 2 dim-chunks, hi/lo of g = -2x.
    short8 fH[2], fL[2];
    {
        int pos = wavePos + lc;
        int b   = pos >> 12;
        int hw  = pos & (HWSZ - 1);
        const float* xb = in + ((size_t)b << 18) + hw;
        #pragma unroll
        for (int c = 0; c < 2; ++c) {
            short8 h, lo;
            #pragma unroll
            for (int j = 0; j < 8; ++j) {
                int d = 32 * c + lg * 8 + j;
                float g = -2.0f * xb[(size_t)d << 12];
                unsigned short hb = bf16rne(g);
                float hf = bf16tof(hb);
                unsigned short lb = bf16rne(g - hf);
                h[j]  = (short)hb;
                lo[j] = (short)lb;
            }
            fH[c] = h;
            fL[c] = lo;
        }
    }

    float m1[4], m2[4], m3[4];
    int   i1[4], i2[4];
    #pragma unroll
    for (int r = 0; r < 4; ++r) {
        m1[r] = 3.4e38f; m2[r] = 3.4e38f; m3[r] = 3.4e38f;
        i1[r] = 0;       i2[r] = 0;
    }

    short8 ceh0 = bfrag[lane],       cel0 = bfrag[64 + lane];
    short8 ceh1 = bfrag[128 + lane], cel1 = bfrag[192 + lane];
    float  ce2  = e2np[lc];
    #pragma unroll 2
    for (int t = 0; t < 32; ++t) {
        short8 neh0, nel0, neh1, nel1;
        float  ne2 = 0.0f;
        if (t < 31) {
            const short8* nb = bfrag + (t + 1) * 256;
            neh0 = nb[lane];       nel0 = nb[64 + lane];
            neh1 = nb[128 + lane]; nel1 = nb[192 + lane];
            ne2  = e2np[(t + 1) * 16 + lc];
        }
        const int kf = t * 16 + lc;
        float4v aH = {ce2, ce2, ce2, ce2};
        float4v aM = {0.f, 0.f, 0.f, 0.f};
        float4v aL = {0.f, 0.f, 0.f, 0.f};
        aH = __builtin_amdgcn_mfma_f32_16x16x32_bf16(fH[0], ceh0, aH, 0, 0, 0);
        aM = __builtin_amdgcn_mfma_f32_16x16x32_bf16(fH[0], cel0, aM, 0, 0, 0);
        aL = __builtin_amdgcn_mfma_f32_16x16x32_bf16(fL[0], ceh0, aL, 0, 0, 0);
        aH = __builtin_amdgcn_mfma_f32_16x16x32_bf16(fH[1], ceh1, aH, 0, 0, 0);
        aM = __builtin_amdgcn_mfma_f32_16x16x32_bf16(fH[1], cel1, aM, 0, 0, 0);
        aL = __builtin_amdgcn_mfma_f32_16x16x32_bf16(fL[1], ceh1, aL, 0, 0, 0);
        #pragma unroll
        for (int r = 0; r < 4; ++r) {
            float sv = (aH[r] + aM[r]) + aL[r];
            INS(m1[r], i1[r], m2[r], i2[r], m3[r], sv, kf);
        }
        ceh0 = neh0; cel0 = nel0; ceh1 = neh1; cel1 = nel1; ce2 = ne2;
    }

    // cross-lane top-3 merge over the 16-lane code group
    #pragma unroll
    for (int r = 0; r < 4; ++r) {
        float M1 = m1[r], M2 = m2[r], M3 = m3[r];
        int   I1 = i1[r], I2 = i2[r];
        #pragma unroll
        for (int d = 1; d <= 8; d <<= 1) {
            float pm1 = __shfl_xor(M1, d, 64);
            int   pi1 = __shfl_xor(I1, d, 64);
            float pm2 = __shfl_xor(M2, d, 64);
            int   pi2 = __shfl_xor(I2, d, 64);
            float pm3 = __shfl_xor(M3, d, 64);
            INS(M1, I1, M2, I2, M3, pm1, pi1);
            INS(M1, I1, M2, I2, M3, pm2, pi2);
            M3 = fminf(M3, pm3);    // pm3 >= pm2 >= post-insert M2
        }
        m1[r] = M1; m2[r] = M2; m3[r] = M3;
        i1[r] = I1; i2[r] = I2;
    }

    if (lc == 0) {
        #pragma unroll
        for (int r = 0; r < 4; ++r) {
            int p  = wavePos + lg * 4 + r;
            bool g2 = (m2[r] - m1[r] <= DELTA);
            bool g3 = (m3[r] - m1[r] <= DELTA);
            if (!g2 && !g3) {
                out_idx[p] = (float)i1[r];     // PLAIN: final for the writer
            } else {
                int packed = i1[r] | (i2[r] << 9)
                           | (1 << 18) | (g3 ? (1 << 19) : 0);
                out_idx[p] = (float)packed;    // < 2^20: exact in fp32
                if (g3) {
                    unsigned slot = atomicAdd(fullCnt, 1u);
                    if (slot < (unsigned)fullCap) fullList[slot] = (unsigned)p;
                }
            }
        }
    }
}

// ---------- full-scan: WAVE per listed position, 8 codes/lane (R12) -------
__global__ __launch_bounds__(64) void vq_full(
        const float* __restrict__ in, const float* __restrict__ emb,
        const float* __restrict__ e2np, const unsigned* __restrict__ fullCnt,
        const unsigned* __restrict__ fullList, int fullCap,
        float* __restrict__ out_idx) {
    __shared__ float xbuf[EMB];
    const int lane = threadIdx.x;
    unsigned cnt = *fullCnt;
    if (cnt > (unsigned)fullCap) cnt = (unsigned)fullCap;

    for (unsigned idx = blockIdx.x; idx < cnt; idx += gridDim.x) {
        const int n  = (int)fullList[idx];
        const int b  = n >> 12;
        const int hw = n & (HWSZ - 1);
        xbuf[lane] = in[((size_t)b << 18) + ((size_t)lane << 12) + hw];
        __syncthreads();

        float x2;
        {
            #pragma clang fp contract(off)
            float r0 = xbuf[0] * xbuf[0], r1 = xbuf[1] * xbuf[1];
            float r2 = xbuf[2] * xbuf[2], r3 = xbuf[3] * xbuf[3];
            float r4 = xbuf[4] * xbuf[4], r5 = xbuf[5] * xbuf[5];
            float r6 = xbuf[6] * xbuf[6], r7 = xbuf[7] * xbuf[7];
            #pragma unroll 1
            for (int i = 8; i < EMB; i += 8) {
                r0 += xbuf[i + 0] * xbuf[i + 0];
                r1 += xbuf[i + 1] * xbuf[i + 1];
                r2 += xbuf[i + 2] * xbuf[i + 2];
                r3 += xbuf[i + 3] * xbuf[i + 3];
                r4 += xbuf[i + 4] * xbuf[i + 4];
                r5 += xbuf[i + 5] * xbuf[i + 5];
                r6 += xbuf[i + 6] * xbuf[i + 6];
                r7 += xbuf[i + 7] * xbuf[i + 7];
            }
            x2 = ((r0 + r1) + (r2 + r3)) + ((r4 + r5) + (r6 + r7));
        }

        float bu = 3.4e38f;
        int   bk = 0x7fffffff;
        #pragma unroll 1
        for (int j = 0; j < 8; ++j) {
            const int k = j * 64 + lane;
            const float* ek = emb + (size_t)k * EMB;
            float t0 = 0.f, t1 = 0.f, t2 = 0.f, t3 = 0.f;
            #pragma unroll 4
            for (int c = 0; c < EMB; c += 4) {
                t0 = fmaf(xbuf[c + 0], ek[c + 0], t0);
                t1 = fmaf(xbuf[c + 1], ek[c + 1], t1);
                t2 = fmaf(xbuf[c + 2], ek[c + 2], t2);
                t3 = fmaf(xbuf[c + 3], ek[c + 3], t3);
            }
            float xe  = (t0 + t1) + (t2 + t3);
            float tmp = x2 - 2.0f * xe;
            float u   = tmp + e2np[k];
            if (u < bu || (u == bu && k < bk)) { bu = u; bk = k; }
        }
        #pragma unroll
        for (int d = 1; d < 64; d <<= 1) {
            float ou = __shfl_xor(bu, d, 64);
            int   ok = __shfl_xor(bk, d, 64);
            if (ou < bu || (ou == bu && ok < bk)) { bu = ou; bk = ok; }
        }
        if (lane == 0) out_idx[n] = (float)bk;   // plain index, flags cleared
        __syncthreads();
    }
}

// ---------- res2: 1t/pos sweep, finish ALL remaining resolution ----------
// fl==0 (plain): exit (95%). g2-only: depth-2 exact resolve. fl&2 leftover
// = list overflow only (vq_full ran first): loop-based exact full scan
// (never executed in practice; codegen isolated here, away from writer).
__global__ __launch_bounds__(256) void vq_res2(
        const float* __restrict__ in, const float* __restrict__ emb,
        const float* __restrict__ e2np, float* __restrict__ out_idx) {
    const int n = blockIdx.x * 256 + threadIdx.x;
    const int v = (int)out_idx[n];
    const int fl = v >> 18;
    if (!fl) return;
    const int b  = n >> 12;
    const int hw = n & (HWSZ - 1);
    const float* xp = in + ((size_t)b << 18) + hw;
    float x[EMB];
    #pragma unroll
    for (int c = 0; c < EMB; ++c) x[c] = xp[(size_t)c << 12];
    const float x2 = np_sumsq64(x);
    int kk;
    if (fl & 2) {
        // overflow safety net: exact full scan, first-min semantics
        float bu = 3.4e38f; int bk = 0;
        for (int k = 0; k < KCODE; ++k) {
            float u = exact_u(x, x2, emb + k * EMB, e2np[k]);
            if (u < bu) { bu = u; bk = k; }
        }
        kk = bk;
    } else {
        const int ia = v & 511, ib = (v >> 9) & 511;
        float u1 = exact_u(x, x2, emb + (size_t)ia * EMB, e2np[ia]);
        float u2 = exact_u(x, x2, emb + (size_t)ib * EMB, e2np[ib]);
        kk = (u1 < u2) ? ia : (u2 < u1 ? ib : (ia < ib ? ia : ib));
    }
    out_idx[n] = (float)kk;
}

// ---------- writer: float4-along-hw, 4 positions x 16 dims per thread -----
// quarter = g>>15: all 64 lanes of a wave share the dim-plane -> every
// load/store is 64 lanes x 16B = 1KB contiguous. 49 VMEM/thread.
__global__ __launch_bounds__(256) void vq_write(
        const float* __restrict__ in, const float* __restrict__ emb,
        const float* __restrict__ out_idx, float* __restrict__ out_q,
        float* __restrict__ partials,           // ws+8, [512]
        unsigned* __restrict__ ticket,          // ws+1
        float* __restrict__ out_loss) {
    const int tid  = threadIdx.x;
    const int wave = tid >> 6;
    const int lane = tid & 63;
    const int g    = blockIdx.x * 256 + tid;    // 0..131071
    const int pg   = g & 32767;                 // position group (4 pos)
    const int qt   = g >> 15;                   // dim quarter (0..3)
    const int p0   = pg << 2;
    const int b    = p0 >> 12;
    const int hw0  = p0 & (HWSZ - 1);
    const int d0   = qt << 4;

    // 4 plain indices (contract: screen/full/res2 finished all resolution)
    float4 vi = *(const float4*)(out_idx + p0);
    const int k0 = (int)vi.x, k1 = (int)vi.y, k2 = (int)vi.z, k3 = (int)vi.w;
    const float* e0 = emb + (size_t)k0 * EMB + d0;
    const float* e1 = emb + (size_t)k1 * EMB + d0;
    const float* e2 = emb + (size_t)k2 * EMB + d0;
    const float* e3 = emb + (size_t)k3 * EMB + d0;

    const size_t base = ((size_t)b << 18) + ((size_t)d0 << 12) + hw0;
    const float* xp = in    + base;
    float*       op = out_q + base;

    float s = 0.0f;
    #pragma unroll
    for (int j = 0; j < 4; ++j) {               // 4-dim group: d = d0+4j..+3
        float4 q0 = *(const float4*)(e0 + 4 * j);   // position-major gathers
        float4 q1 = *(const float4*)(e1 + 4 * j);
        float4 q2 = *(const float4*)(e2 + 4 * j);
        float4 q3 = *(const float4*)(e3 + 4 * j);
        // dim-major x loads / stores (contiguous along hw)
        #pragma unroll
        for (int dd = 0; dd < 4; ++dd) {
            const size_t off = ((size_t)(4 * j + dd) << 12);
            float4 xv = *(const float4*)(xp + off);
            float4 ov;
            ov.x = dd == 0 ? q0.x : dd == 1 ? q0.y : dd == 2 ? q0.z : q0.w;
            ov.y = dd == 0 ? q1.x : dd == 1 ? q1.y : dd == 2 ? q1.z : q1.w;
            ov.z = dd == 0 ? q2.x : dd == 1 ? q2.y : dd == 2 ? q2.z : q2.w;
            ov.w = dd == 0 ? q3.x : dd == 1 ? q3.y : dd == 2 ? q3.z : q3.w;
            float u0 = ov.x - xv.x, u1 = ov.y - xv.y;
            float u2 = ov.z - xv.z, u3 = ov.w - xv.w;
            s = fmaf(u0, u0, s); s = fmaf(u1, u1, s);
            s = fmaf(u2, u2, s); s = fmaf(u3, u3, s);
            *(float4*)(op + off) = ov;
        }
    }

    // loss: wave shuffle -> LDS -> block partial -> last-block ticket
    #pragma unroll
    for (int off = 32; off > 0; off >>= 1)
        s += __shfl_down(s, off, 64);
    __shared__ float red[4];
    if (lane == 0) red[wave] = s;
    __syncthreads();
    if (tid == 0) {
        partials[blockIdx.x] = (red[0] + red[1]) + (red[2] + red[3]);
        __threadfence();
        unsigned tk = atomicAdd(ticket, 1u);
        if (tk == 511u) {
            __threadfence();
            float a0 = 0.f, a1 = 0.f, a2 = 0.f, a3 = 0.f;
            float a4 = 0.f, a5 = 0.f, a6 = 0.f, a7 = 0.f;
            for (int i = 0; i < 512; i += 8) {
                a0 += partials[i + 0]; a1 += partials[i + 1];
                a2 += partials[i + 2]; a3 += partials[i + 3];
                a4 += partials[i + 4]; a5 += partials[i + 5];
                a6 += partials[i + 6]; a7 += partials[i + 7];
            }
            float tot = ((a0 + a1) + (a2 + a3)) + ((a4 + a5) + (a6 + a7));
            out_loss[0] = 1.25f * tot * (1.0f / ((float)NPOS * (float)EMB));
        }
    }
}

extern "C" void kernel_launch(void* const* d_in, const int* in_sizes, int n_in,
                              void* d_out, int out_size, void* d_ws, size_t ws_size,
                              hipStream_t stream) {
    const float* in  = (const float*)d_in[0];
    const float* emb = (const float*)d_in[1];
    float* ws  = (float*)d_ws;
    float* out = (float*)d_out;

    float*    out_loss = out;
    float*    out_q    = out + 1;
    float*    out_idx  = out + 1 + (size_t)NPOS * EMB;
    unsigned* fullCnt  = (unsigned*)ws;          // ws[0]
    unsigned* ticket   = (unsigned*)ws + 1;      // ws[1]
    float*    partials = ws + 8;                 // [512]
    float*    e2np     = ws + 1032;              // [512]
    short8*   bfrag    = (short8*)(ws + 1544);   // 128 KB
    unsigned* fullList = (unsigned*)(ws + 34312);

    // g3 list capacity limited by what the workspace provably holds;
    // shrinkage only triggers res2's (correct) overflow path.
    long avail = (long)(ws_size / 4) - 34312;
    int  fullCap = avail > 0 ? (avail > 1024 ? 1024 : (int)avail) : 0;

    vq_prep<<<16, 256, 0, stream>>>(emb, ws);
    vq_screen<<<NPOS / 64, 256, 0, stream>>>(in, e2np, bfrag, out_idx,
                                             fullCnt, fullList, fullCap);
    vq_full<<<256, 64, 0, stream>>>(in, emb, e2np, fullCnt, fullList, fullCap,
                                    out_idx);
    vq_res2<<<NPOS / 256, 256, 0, stream>>>(in, emb, e2np, out_idx);
    vq_write<<<NPOS / 256, 256, 0, stream>>>(in, emb, out_idx, out_q,
                                             partials, ticket, out_loss);
}

// Round 18
// 180.907 us; speedup vs baseline: 1.1650x; 1.0141x over previous
//
#include <hip/hip_runtime.h>

// VQ-VAE VectorQuantizer: B=32, C=D=64, H=W=64, K=512
// d_in[0]: inputs  [32,64,64,64] f32 (NCHW, C = embedding dim)
// d_in[1]: embedding [512,64] f32
// d_out: [loss(1) | out(32*64*64*64) | indices(32*4096)] all read as f32
//
// V20 = R17 (183.5us; screen 59 + write<57 + rest) with ONE change:
// the screen's bfrag stream is LDS-staged per block (double-buffered).
// At pt=1 every wave streamed the full 128KB bfrag: 8192 waves x 32t x 4KB
// = 1.07GB of L2 reads (~31us at 34.5TB/s) inside the 59us screen. The 4
// waves of a block read the SAME stream -> stage each 4KB tile once per
// block: 1.07GB -> 268MB (~8us). Single barrier per t-iter (31 total;
// write targets the buffer last read two phases ago, fenced by the
// previous iteration's end barrier), 2-tile-ahead global prefetch.
// Data path bit-identical (same short8 values via LDS).
// Everything else R17 byte-for-byte (R17 passed): plain/packed emit,
// wave-parallel vq_full, res2 sweep, float4-along-hw writer.
// Correctness: screen diff-error <= ~1e-4 < DELTA=2.5e-4; {i1,i2} cover
// argmin unless g3 escalates; exact path = round-0-proven fmaf/pairwise-8
// ordering; first-min kept. Loss partial order changes only (tolerance-
// proven across all rounds).

#define KCODE 512
#define EMB   64
#define HWSZ  4096
#define NPOS  131072
#define DELTA 2.5e-4f

typedef short short8  __attribute__((ext_vector_type(8)));
typedef float float4v __attribute__((ext_vector_type(4)));

// ws float layout (V20 == V19):
//   [0] fullCnt (uint)   [1] writer ticket (uint)   [2..7] pad
//   [8..519]      writer block partials (512)
//   [1032..1543]  e2 (numpy rounding, by code)
//   [1544..34311] bfrag short8[32][2][2][64] (128 KB)
//   [34312..]     g3 full-scan list (cap from ws_size, <=1024)

// ---------- numpy-exact helpers ----------
__device__ __forceinline__ float np_sumsq64(const float* a) {
    #pragma clang fp contract(off)
    {
        float r0 = a[0] * a[0], r1 = a[1] * a[1], r2 = a[2] * a[2], r3 = a[3] * a[3];
        float r4 = a[4] * a[4], r5 = a[5] * a[5], r6 = a[6] * a[6], r7 = a[7] * a[7];
        for (int i = 8; i < 64; i += 8) {
            r0 += a[i + 0] * a[i + 0];
            r1 += a[i + 1] * a[i + 1];
            r2 += a[i + 2] * a[i + 2];
            r3 += a[i + 3] * a[i + 3];
            r4 += a[i + 4] * a[i + 4];
            r5 += a[i + 5] * a[i + 5];
            r6 += a[i + 6] * a[i + 6];
            r7 += a[i + 7] * a[i + 7];
        }
        return ((r0 + r1) + (r2 + r3)) + ((r4 + r5) + (r6 + r7));
    }
}

// exact numpy distance: u = fl(fl(x2 - 2*xe) + e2k)  (round-0-proven order)
__device__ __forceinline__ float exact_u(const float* x, float x2,
                                         const float* ek, float e2k) {
    float t0 = 0.f, t1 = 0.f, t2 = 0.f, t3 = 0.f;
    #pragma unroll
    for (int c = 0; c < EMB; c += 4) {
        t0 = fmaf(x[c + 0], ek[c + 0], t0);
        t1 = fmaf(x[c + 1], ek[c + 1], t1);
        t2 = fmaf(x[c + 2], ek[c + 2], t2);
        t3 = fmaf(x[c + 3], ek[c + 3], t3);
    }
    float xe  = (t0 + t1) + (t2 + t3);
    float tmp = x2 - 2.0f * xe;     // 2*xe exact -> contraction rounding-identical
    return tmp + e2k;
}

__device__ __forceinline__ unsigned short bf16rne(float f) {
    unsigned u = __float_as_uint(f);
    unsigned r = (u + 0x7FFFu + ((u >> 16) & 1u)) >> 16;
    return (unsigned short)r;
}
__device__ __forceinline__ float bf16tof(unsigned short h) {
    return __uint_as_float((unsigned)h << 16);
}

// sorted-insert of (v,i) into ((M1,I1),(M2,I2),M3); strict < keeps earlier.
#define INS(M1, I1, M2, I2, M3, v, i)                      \
    {                                                      \
        bool lt1 = (v) < (M1), lt2 = (v) < (M2), lt3 = (v) < (M3); \
        (M3) = lt2 ? (M2) : (lt3 ? (v) : (M3));            \
        (I2) = lt1 ? (I1) : (lt2 ? (i) : (I2));            \
        (M2) = lt1 ? (M1) : (lt2 ? (v) : (M2));            \
        (M1) = lt1 ? (v) : (M1);                           \
        (I1) = lt1 ? (i) : (I1);                           \
    }

// ---------- prep: e2 + bfrag + counter zeroing ----------
__global__ void vq_prep(const float* __restrict__ emb, float* __restrict__ ws) {
    int f = blockIdx.x * blockDim.x + threadIdx.x;   // 0..4095
    if (f == 0) { ((unsigned*)ws)[0] = 0u; ((unsigned*)ws)[1] = 0u; }
    if (f < KCODE) ws[1032 + f] = np_sumsq64(emb + f * EMB);
    short8* bfrag = (short8*)(ws + 1544);
    int l = f & 63;
    int c = (f >> 6) & 1;
    int t = f >> 7;            // 0..31
    int code  = t * 16 + (l & 15);
    int dbase = 32 * c + ((l >> 4) & 3) * 8;
    const float* e = emb + code * EMB + dbase;
    short8 h, lo;
    #pragma unroll
    for (int j = 0; j < 8; ++j) {
        float v = e[j];
        unsigned short hb = bf16rne(v);
        float hf = bf16tof(hb);
        unsigned short lb = bf16rne(v - hf);
        h[j]  = (short)hb;
        lo[j] = (short)lb;
    }
    bfrag[t * 256 + c * 128 + 0 * 64 + l] = h;
    bfrag[t * 256 + c * 128 + 1 * 64 + l] = lo;
}

// ---------- screen: pt=1 MFMA sweep + LDS-staged bfrag (V20) ----------
__global__ __launch_bounds__(256, 6) void vq_screen(
        const float*  __restrict__ in,
        const float*  __restrict__ e2np,      // ws+1032
        const short8* __restrict__ bfrag,     // ws+1544
        float*        __restrict__ out_idx,   // plain i1 OR packed+flags
        unsigned*     __restrict__ fullCnt,   // ws+0
        unsigned*     __restrict__ fullList,  // ws+34312
        int fullCap) {
    __shared__ short8 sbuf[2][256];           // double-buffered 4KB tiles
    const int tid  = threadIdx.x;
    const int wave = tid >> 6;
    const int lane = tid & 63;
    const int lg   = lane >> 4;
    const int lc   = lane & 15;
    const int wavePos = blockIdx.x * 64 + wave * 16;   // 16 positions/wave

    // A-fragments: 1 pos-tile x 2 dim-chunks, hi/lo of g = -2x.
    short8 fH[2], fL[2];
    {
        int pos = wavePos + lc;
        int b   = pos >> 12;
        int hw  = pos & (HWSZ - 1);
        const float* xb = in + ((size_t)b << 18) + hw;
        #pragma unroll
        for (int c = 0; c < 2; ++c) {
            short8 h, lo;
            #pragma unroll
            for (int j = 0; j < 8; ++j) {
                int d = 32 * c + lg * 8 + j;
                float g = -2.0f * xb[(size_t)d << 12];
                unsigned short hb = bf16rne(g);
                float hf = bf16tof(hb);
                unsigned short lb = bf16rne(g - hf);
                h[j]  = (short)hb;
                lo[j] = (short)lb;
            }
            fH[c] = h;
            fL[c] = lo;
        }
    }

    float m1[4], m2[4], m3[4];
    int   i1[4], i2[4];
    #pragma unroll
    for (int r = 0; r < 4; ++r) {
        m1[r] = 3.4e38f; m2[r] = 3.4e38f; m3[r] = 3.4e38f;
        i1[r] = 0;       i2[r] = 0;
    }

    // stage tile 0, prefetch tile 1 into registers
    sbuf[0][tid] = bfrag[tid];
    short8 nreg = bfrag[256 + tid];
    __syncthreads();

    for (int t = 0; t < 32; ++t) {
        const short8* sb = sbuf[t & 1];
        const short8 ceh0 = sb[lane];
        const short8 cel0 = sb[64 + lane];
        const short8 ceh1 = sb[128 + lane];
        const short8 cel1 = sb[192 + lane];
        const float  ce2  = e2np[t * 16 + lc];
        const int    kf   = t * 16 + lc;

        float4v aH = {ce2, ce2, ce2, ce2};
        float4v aM = {0.f, 0.f, 0.f, 0.f};
        float4v aL = {0.f, 0.f, 0.f, 0.f};
        aH = __builtin_amdgcn_mfma_f32_16x16x32_bf16(fH[0], ceh0, aH, 0, 0, 0);
        aM = __builtin_amdgcn_mfma_f32_16x16x32_bf16(fH[0], cel0, aM, 0, 0, 0);
        aL = __builtin_amdgcn_mfma_f32_16x16x32_bf16(fL[0], ceh0, aL, 0, 0, 0);
        aH = __builtin_amdgcn_mfma_f32_16x16x32_bf16(fH[1], ceh1, aH, 0, 0, 0);
        aM = __builtin_amdgcn_mfma_f32_16x16x32_bf16(fH[1], cel1, aM, 0, 0, 0);
        aL = __builtin_amdgcn_mfma_f32_16x16x32_bf16(fL[1], ceh1, aL, 0, 0, 0);
        #pragma unroll
        for (int r = 0; r < 4; ++r) {
            float sv = (aH[r] + aM[r]) + aL[r];
            INS(m1[r], i1[r], m2[r], i2[r], m3[r], sv, kf);
        }

        if (t < 31) {
            // write tile t+1 into the OTHER buffer. Its last readers were at
            // compute(t-1), fenced by iteration t-1's end barrier. Readers of
            // this write are at compute(t+1), fenced by THIS barrier.
            sbuf[(t & 1) ^ 1][tid] = nreg;
            if (t < 30) nreg = bfrag[(t + 2) * 256 + tid];
            __syncthreads();
        }
    }

    // cross-lane top-3 merge over the 16-lane code group
    #pragma unroll
    for (int r = 0; r < 4; ++r) {
        float M1 = m1[r], M2 = m2[r], M3 = m3[r];
        int   I1 = i1[r], I2 = i2[r];
        #pragma unroll
        for (int d = 1; d <= 8; d <<= 1) {
            float pm1 = __shfl_xor(M1, d, 64);
            int   pi1 = __shfl_xor(I1, d, 64);
            float pm2 = __shfl_xor(M2, d, 64);
            int   pi2 = __shfl_xor(I2, d, 64);
            float pm3 = __shfl_xor(M3, d, 64);
            INS(M1, I1, M2, I2, M3, pm1, pi1);
            INS(M1, I1, M2, I2, M3, pm2, pi2);
            M3 = fminf(M3, pm3);    // pm3 >= pm2 >= post-insert M2
        }
        m1[r] = M1; m2[r] = M2; m3[r] = M3;
        i1[r] = I1; i2[r] = I2;
    }

    if (lc == 0) {
        #pragma unroll
        for (int r = 0; r < 4; ++r) {
            int p  = wavePos + lg * 4 + r;
            bool g2 = (m2[r] - m1[r] <= DELTA);
            bool g3 = (m3[r] - m1[r] <= DELTA);
            if (!g2 && !g3) {
                out_idx[p] = (float)i1[r];     // PLAIN: final for the writer
            } else {
                int packed = i1[r] | (i2[r] << 9)
                           | (1 << 18) | (g3 ? (1 << 19) : 0);
                out_idx[p] = (float)packed;    // < 2^20: exact in fp32
                if (g3) {
                    unsigned slot = atomicAdd(fullCnt, 1u);
                    if (slot < (unsigned)fullCap) fullList[slot] = (unsigned)p;
                }
            }
        }
    }
}

// ---------- full-scan: WAVE per listed position, 8 codes/lane (R12) -------
__global__ __launch_bounds__(64) void vq_full(
        const float* __restrict__ in, const float* __restrict__ emb,
        const float* __restrict__ e2np, const unsigned* __restrict__ fullCnt,
        const unsigned* __restrict__ fullList, int fullCap,
        float* __restrict__ out_idx) {
    __shared__ float xbuf[EMB];
    const int lane = threadIdx.x;
    unsigned cnt = *fullCnt;
    if (cnt > (unsigned)fullCap) cnt = (unsigned)fullCap;

    for (unsigned idx = blockIdx.x; idx < cnt; idx += gridDim.x) {
        const int n  = (int)fullList[idx];
        const int b  = n >> 12;
        const int hw = n & (HWSZ - 1);
        xbuf[lane] = in[((size_t)b << 18) + ((size_t)lane << 12) + hw];
        __syncthreads();

        float x2;
        {
            #pragma clang fp contract(off)
            float r0 = xbuf[0] * xbuf[0], r1 = xbuf[1] * xbuf[1];
            float r2 = xbuf[2] * xbuf[2], r3 = xbuf[3] * xbuf[3];
            float r4 = xbuf[4] * xbuf[4], r5 = xbuf[5] * xbuf[5];
            float r6 = xbuf[6] * xbuf[6], r7 = xbuf[7] * xbuf[7];
            #pragma unroll 1
            for (int i = 8; i < EMB; i += 8) {
                r0 += xbuf[i + 0] * xbuf[i + 0];
                r1 += xbuf[i + 1] * xbuf[i + 1];
                r2 += xbuf[i + 2] * xbuf[i + 2];
                r3 += xbuf[i + 3] * xbuf[i + 3];
                r4 += xbuf[i + 4] * xbuf[i + 4];
                r5 += xbuf[i + 5] * xbuf[i + 5];
                r6 += xbuf[i + 6] * xbuf[i + 6];
                r7 += xbuf[i + 7] * xbuf[i + 7];
            }
            x2 = ((r0 + r1) + (r2 + r3)) + ((r4 + r5) + (r6 + r7));
        }

        float bu = 3.4e38f;
        int   bk = 0x7fffffff;
        #pragma unroll 1
        for (int j = 0; j < 8; ++j) {
            const int k = j * 64 + lane;
            const float* ek = emb + (size_t)k * EMB;
            float t0 = 0.f, t1 = 0.f, t2 = 0.f, t3 = 0.f;
            #pragma unroll 4
            for (int c = 0; c < EMB; c += 4) {
                t0 = fmaf(xbuf[c + 0], ek[c + 0], t0);
                t1 = fmaf(xbuf[c + 1], ek[c + 1], t1);
                t2 = fmaf(xbuf[c + 2], ek[c + 2], t2);
                t3 = fmaf(xbuf[c + 3], ek[c + 3], t3);
            }
            float xe  = (t0 + t1) + (t2 + t3);
            float tmp = x2 - 2.0f * xe;
            float u   = tmp + e2np[k];
            if (u < bu || (u == bu && k < bk)) { bu = u; bk = k; }
        }
        #pragma unroll
        for (int d = 1; d < 64; d <<= 1) {
            float ou = __shfl_xor(bu, d, 64);
            int   ok = __shfl_xor(bk, d, 64);
            if (ou < bu || (ou == bu && ok < bk)) { bu = ou; bk = ok; }
        }
        if (lane == 0) out_idx[n] = (float)bk;   // plain index, flags cleared
        __syncthreads();
    }
}

// ---------- res2: 1t/pos sweep, finish ALL remaining resolution ----------
// fl==0 (plain): exit (95%). g2-only: depth-2 exact resolve. fl&2 leftover
// = list overflow only (vq_full ran first): loop-based exact full scan
// (never executed in practice; codegen isolated here, away from writer).
__global__ __launch_bounds__(256) void vq_res2(
        const float* __restrict__ in, const float* __restrict__ emb,
        const float* __restrict__ e2np, float* __restrict__ out_idx) {
    const int n = blockIdx.x * 256 + threadIdx.x;
    const int v = (int)out_idx[n];
    const int fl = v >> 18;
    if (!fl) return;
    const int b  = n >> 12;
    const int hw = n & (HWSZ - 1);
    const float* xp = in + ((size_t)b << 18) + hw;
    float x[EMB];
    #pragma unroll
    for (int c = 0; c < EMB; ++c) x[c] = xp[(size_t)c << 12];
    const float x2 = np_sumsq64(x);
    int kk;
    if (fl & 2) {
        // overflow safety net: exact full scan, first-min semantics
        float bu = 3.4e38f; int bk = 0;
        for (int k = 0; k < KCODE; ++k) {
            float u = exact_u(x, x2, emb + k * EMB, e2np[k]);
            if (u < bu) { bu = u; bk = k; }
        }
        kk = bk;
    } else {
        const int ia = v & 511, ib = (v >> 9) & 511;
        float u1 = exact_u(x, x2, emb + (size_t)ia * EMB, e2np[ia]);
        float u2 = exact_u(x, x2, emb + (size_t)ib * EMB, e2np[ib]);
        kk = (u1 < u2) ? ia : (u2 < u1 ? ib : (ia < ib ? ia : ib));
    }
    out_idx[n] = (float)kk;
}

// ---------- writer: float4-along-hw, 4 positions x 16 dims per thread -----
// quarter = g>>15: all 64 lanes of a wave share the dim-plane -> every
// load/store is 64 lanes x 16B = 1KB contiguous. 49 VMEM/thread.
__global__ __launch_bounds__(256) void vq_write(
        const float* __restrict__ in, const float* __restrict__ emb,
        const float* __restrict__ out_idx, float* __restrict__ out_q,
        float* __restrict__ partials,           // ws+8, [512]
        unsigned* __restrict__ ticket,          // ws+1
        float* __restrict__ out_loss) {
    const int tid  = threadIdx.x;
    const int wave = tid >> 6;
    const int lane = tid & 63;
    const int g    = blockIdx.x * 256 + tid;    // 0..131071
    const int pg   = g & 32767;                 // position group (4 pos)
    const int qt   = g >> 15;                   // dim quarter (0..3)
    const int p0   = pg << 2;
    const int b    = p0 >> 12;
    const int hw0  = p0 & (HWSZ - 1);
    const int d0   = qt << 4;

    // 4 plain indices (contract: screen/full/res2 finished all resolution)
    float4 vi = *(const float4*)(out_idx + p0);
    const int k0 = (int)vi.x, k1 = (int)vi.y, k2 = (int)vi.z, k3 = (int)vi.w;
    const float* e0 = emb + (size_t)k0 * EMB + d0;
    const float* e1 = emb + (size_t)k1 * EMB + d0;
    const float* e2 = emb + (size_t)k2 * EMB + d0;
    const float* e3 = emb + (size_t)k3 * EMB + d0;

    const size_t base = ((size_t)b << 18) + ((size_t)d0 << 12) + hw0;
    const float* xp = in    + base;
    float*       op = out_q + base;

    float s = 0.0f;
    #pragma unroll
    for (int j = 0; j < 4; ++j) {               // 4-dim group: d = d0+4j..+3
        float4 q0 = *(const float4*)(e0 + 4 * j);   // position-major gathers
        float4 q1 = *(const float4*)(e1 + 4 * j);
        float4 q2 = *(const float4*)(e2 + 4 * j);
        float4 q3 = *(const float4*)(e3 + 4 * j);
        // dim-major x loads / stores (contiguous along hw)
        #pragma unroll
        for (int dd = 0; dd < 4; ++dd) {
            const size_t off = ((size_t)(4 * j + dd) << 12);
            float4 xv = *(const float4*)(xp + off);
            float4 ov;
            ov.x = dd == 0 ? q0.x : dd == 1 ? q0.y : dd == 2 ? q0.z : q0.w;
            ov.y = dd == 0 ? q1.x : dd == 1 ? q1.y : dd == 2 ? q1.z : q1.w;
            ov.z = dd == 0 ? q2.x : dd == 1 ? q2.y : dd == 2 ? q2.z : q2.w;
            ov.w = dd == 0 ? q3.x : dd == 1 ? q3.y : dd == 2 ? q3.z : q3.w;
            float u0 = ov.x - xv.x, u1 = ov.y - xv.y;
            float u2 = ov.z - xv.z, u3 = ov.w - xv.w;
            s = fmaf(u0, u0, s); s = fmaf(u1, u1, s);
            s = fmaf(u2, u2, s); s = fmaf(u3, u3, s);
            *(float4*)(op + off) = ov;
        }
    }

    // loss: wave shuffle -> LDS -> block partial -> last-block ticket
    #pragma unroll
    for (int off = 32; off > 0; off >>= 1)
        s += __shfl_down(s, off, 64);
    __shared__ float red[4];
    if (lane == 0) red[wave] = s;
    __syncthreads();
    if (tid == 0) {
        partials[blockIdx.x] = (red[0] + red[1]) + (red[2] + red[3]);
        __threadfence();
        unsigned tk = atomicAdd(ticket, 1u);
        if (tk == 511u) {
            __threadfence();
            float a0 = 0.f, a1 = 0.f, a2 = 0.f, a3 = 0.f;
            float a4 = 0.f, a5 = 0.f, a6 = 0.f, a7 = 0.f;
            for (int i = 0; i < 512; i += 8) {
                a0 += partials[i + 0]; a1 += partials[i + 1];
                a2 += partials[i + 2]; a3 += partials[i + 3];
                a4 += partials[i + 4]; a5 += partials[i + 5];
                a6 += partials[i + 6]; a7 += partials[i + 7];
            }
            float tot = ((a0 + a1) + (a2 + a3)) + ((a4 + a5) + (a6 + a7));
            out_loss[0] = 1.25f * tot * (1.0f / ((float)NPOS * (float)EMB));
        }
    }
}

extern "C" void kernel_launch(void* const* d_in, const int* in_sizes, int n_in,
                              void* d_out, int out_size, void* d_ws, size_t ws_size,
                              hipStream_t stream) {
    const float* in  = (const float*)d_in[0];
    const float* emb = (const float*)d_in[1];
    float* ws  = (float*)d_ws;
    float* out = (float*)d_out;

    float*    out_loss = out;
    float*    out_q    = out + 1;
    float*    out_idx  = out + 1 + (size_t)NPOS * EMB;
    unsigned* fullCnt  = (unsigned*)ws;          // ws[0]
    unsigned* ticket   = (unsigned*)ws + 1;      // ws[1]
    float*    partials = ws + 8;                 // [512]
    float*    e2np     = ws + 1032;              // [512]
    short8*   bfrag    = (short8*)(ws + 1544);   // 128 KB
    unsigned* fullList = (unsigned*)(ws + 34312);

    // g3 list capacity limited by what the workspace provably holds;
    // shrinkage only triggers res2's (correct) overflow path.
    long avail = (long)(ws_size / 4) - 34312;
    int  fullCap = avail > 0 ? (avail > 1024 ? 1024 : (int)avail) : 0;

    vq_prep<<<16, 256, 0, stream>>>(emb, ws);
    vq_screen<<<NPOS / 64, 256, 0, stream>>>(in, e2np, bfrag, out_idx,
                                             fullCnt, fullList, fullCap);
    vq_full<<<256, 64, 0, stream>>>(in, emb, e2np, fullCnt, fullList, fullCap,
                                    out_idx);
    vq_res2<<<NPOS / 256, 256, 0, stream>>>(in, emb, e2np, out_idx);
    vq_write<<<NPOS / 256, 256, 0, stream>>>(in, emb, out_idx, out_q,
                                             partials, ticket, out_loss);
}

// Round 19
// 176.436 us; speedup vs baseline: 1.1945x; 1.0253x over previous
//
#include <hip/hip_runtime.h>

// VQ-VAE VectorQuantizer: B=32, C=D=64, H=W=64, K=512
// d_in[0]: inputs  [32,64,64,64] f32 (NCHW, C = embedding dim)
// d_in[1]: embedding [512,64] f32
// d_out: [loss(1) | out(32*64*64*64) | indices(32*4096)] all read as f32
//
// V21 = R18 (180.9us) with vq_full+vq_res2 MERGED into one vq_resolve
// kernel (5 -> 4 dispatches). Four rounds flat at 180-184 while component
// wins (screen -20, writer -20) were absorbed: visible kernel time ~120us
// vs 181 total -> ~60us lives at dispatch boundaries/harness. The only
// kernel-side lever on that gap is fewer serialized launches.
// Changes vs R18 (everything else byte-for-byte):
//  - screen emit: g3 sets bit19 ONLY if actually listed (slot<cap), else
//    bit20=overflow. Removes the full->res2 ordering dependency (and a
//    latent stale-bit19 hazard on overflow).
//  - vq_resolve <<<2048,64>>>: phase 1 = R18 res2 body (fl==1 g2 resolve;
//    bit20 serial-scan safety net, statically never; bit19 skip); phase 2
//    = R12 wave-parallel g3 body (1-wave blocks, grid-stride over list).
//    Disjoint positions -> no internal ordering needed.
// Contract: by vq_write, out_idx[p] is a plain index for every p.
// Correctness: screen diff-error <= ~1e-4 < DELTA=2.5e-4; {i1,i2} cover
// argmin unless g3 escalates; exact path = round-0-proven fmaf/pairwise-8
// ordering; first-min kept. Loss partial order changes only (tolerance-
// proven across all rounds).

#define KCODE 512
#define EMB   64
#define HWSZ  4096
#define NPOS  131072
#define DELTA 2.5e-4f

typedef short short8  __attribute__((ext_vector_type(8)));
typedef float float4v __attribute__((ext_vector_type(4)));

// ws float layout (V21 == V19/V20):
//   [0] fullCnt (uint)   [1] writer ticket (uint)   [2..7] pad
//   [8..519]      writer block partials (512)
//   [1032..1543]  e2 (numpy rounding, by code)
//   [1544..34311] bfrag short8[32][2][2][64] (128 KB)
//   [34312..]     g3 full-scan list (cap from ws_size, <=1024)

// ---------- numpy-exact helpers ----------
__device__ __forceinline__ float np_sumsq64(const float* a) {
    #pragma clang fp contract(off)
    {
        float r0 = a[0] * a[0], r1 = a[1] * a[1], r2 = a[2] * a[2], r3 = a[3] * a[3];
        float r4 = a[4] * a[4], r5 = a[5] * a[5], r6 = a[6] * a[6], r7 = a[7] * a[7];
        for (int i = 8; i < 64; i += 8) {
            r0 += a[i + 0] * a[i + 0];
            r1 += a[i + 1] * a[i + 1];
            r2 += a[i + 2] * a[i + 2];
            r3 += a[i + 3] * a[i + 3];
            r4 += a[i + 4] * a[i + 4];
            r5 += a[i + 5] * a[i + 5];
            r6 += a[i + 6] * a[i + 6];
            r7 += a[i + 7] * a[i + 7];
        }
        return ((r0 + r1) + (r2 + r3)) + ((r4 + r5) + (r6 + r7));
    }
}

// exact numpy distance: u = fl(fl(x2 - 2*xe) + e2k)  (round-0-proven order)
__device__ __forceinline__ float exact_u(const float* x, float x2,
                                         const float* ek, float e2k) {
    float t0 = 0.f, t1 = 0.f, t2 = 0.f, t3 = 0.f;
    #pragma unroll
    for (int c = 0; c < EMB; c += 4) {
        t0 = fmaf(x[c + 0], ek[c + 0], t0);
        t1 = fmaf(x[c + 1], ek[c + 1], t1);
        t2 = fmaf(x[c + 2], ek[c + 2], t2);
        t3 = fmaf(x[c + 3], ek[c + 3], t3);
    }
    float xe  = (t0 + t1) + (t2 + t3);
    float tmp = x2 - 2.0f * xe;     // 2*xe exact -> contraction rounding-identical
    return tmp + e2k;
}

__device__ __forceinline__ unsigned short bf16rne(float f) {
    unsigned u = __float_as_uint(f);
    unsigned r = (u + 0x7FFFu + ((u >> 16) & 1u)) >> 16;
    return (unsigned short)r;
}
__device__ __forceinline__ float bf16tof(unsigned short h) {
    return __uint_as_float((unsigned)h << 16);
}

// sorted-insert of (v,i) into ((M1,I1),(M2,I2),M3); strict < keeps earlier.
#define INS(M1, I1, M2, I2, M3, v, i)                      \
    {                                                      \
        bool lt1 = (v) < (M1), lt2 = (v) < (M2), lt3 = (v) < (M3); \
        (M3) = lt2 ? (M2) : (lt3 ? (v) : (M3));            \
        (I2) = lt1 ? (I1) : (lt2 ? (i) : (I2));            \
        (M2) = lt1 ? (M1) : (lt2 ? (v) : (M2));            \
        (M1) = lt1 ? (v) : (M1);                           \
        (I1) = lt1 ? (i) : (I1);                           \
    }

// ---------- prep: e2 + bfrag + counter zeroing ----------
__global__ void vq_prep(const float* __restrict__ emb, float* __restrict__ ws) {
    int f = blockIdx.x * blockDim.x + threadIdx.x;   // 0..4095
    if (f == 0) { ((unsigned*)ws)[0] = 0u; ((unsigned*)ws)[1] = 0u; }
    if (f < KCODE) ws[1032 + f] = np_sumsq64(emb + f * EMB);
    short8* bfrag = (short8*)(ws + 1544);
    int l = f & 63;
    int c = (f >> 6) & 1;
    int t = f >> 7;            // 0..31
    int code  = t * 16 + (l & 15);
    int dbase = 32 * c + ((l >> 4) & 3) * 8;
    const float* e = emb + code * EMB + dbase;
    short8 h, lo;
    #pragma unroll
    for (int j = 0; j < 8; ++j) {
        float v = e[j];
        unsigned short hb = bf16rne(v);
        float hf = bf16tof(hb);
        unsigned short lb = bf16rne(v - hf);
        h[j]  = (short)hb;
        lo[j] = (short)lb;
    }
    bfrag[t * 256 + c * 128 + 0 * 64 + l] = h;
    bfrag[t * 256 + c * 128 + 1 * 64 + l] = lo;
}

// ---------- screen: pt=1 MFMA sweep + LDS-staged bfrag (R18) ----------
__global__ __launch_bounds__(256, 6) void vq_screen(
        const float*  __restrict__ in,
        const float*  __restrict__ e2np,      // ws+1032
        const short8* __restrict__ bfrag,     // ws+1544
        float*        __restrict__ out_idx,   // plain i1 OR packed+flags
        unsigned*     __restrict__ fullCnt,   // ws+0
        unsigned*     __restrict__ fullList,  // ws+34312
        int fullCap) {
    __shared__ short8 sbuf[2][256];           // double-buffered 4KB tiles
    const int tid  = threadIdx.x;
    const int wave = tid >> 6;
    const int lane = tid & 63;
    const int lg   = lane >> 4;
    const int lc   = lane & 15;
    const int wavePos = blockIdx.x * 64 + wave * 16;   // 16 positions/wave

    // A-fragments: 1 pos-tile x 2 dim-chunks, hi/lo of g = -2x.
    short8 fH[2], fL[2];
    {
        int pos = wavePos + lc;
        int b   = pos >> 12;
        int hw  = pos & (HWSZ - 1);
        const float* xb = in + ((size_t)b << 18) + hw;
        #pragma unroll
        for (int c = 0; c < 2; ++c) {
            short8 h, lo;
            #pragma unroll
            for (int j = 0; j < 8; ++j) {
                int d = 32 * c + lg * 8 + j;
                float g = -2.0f * xb[(size_t)d << 12];
                unsigned short hb = bf16rne(g);
                float hf = bf16tof(hb);
                unsigned short lb = bf16rne(g - hf);
                h[j]  = (short)hb;
                lo[j] = (short)lb;
            }
            fH[c] = h;
            fL[c] = lo;
        }
    }

    float m1[4], m2[4], m3[4];
    int   i1[4], i2[4];
    #pragma unroll
    for (int r = 0; r < 4; ++r) {
        m1[r] = 3.4e38f; m2[r] = 3.4e38f; m3[r] = 3.4e38f;
        i1[r] = 0;       i2[r] = 0;
    }

    // stage tile 0, prefetch tile 1 into registers
    sbuf[0][tid] = bfrag[tid];
    short8 nreg = bfrag[256 + tid];
    __syncthreads();

    for (int t = 0; t < 32; ++t) {
        const short8* sb = sbuf[t & 1];
        const short8 ceh0 = sb[lane];
        const short8 cel0 = sb[64 + lane];
        const short8 ceh1 = sb[128 + lane];
        const short8 cel1 = sb[192 + lane];
        const float  ce2  = e2np[t * 16 + lc];
        const int    kf   = t * 16 + lc;

        float4v aH = {ce2, ce2, ce2, ce2};
        float4v aM = {0.f, 0.f, 0.f, 0.f};
        float4v aL = {0.f, 0.f, 0.f, 0.f};
        aH = __builtin_amdgcn_mfma_f32_16x16x32_bf16(fH[0], ceh0, aH, 0, 0, 0);
        aM = __builtin_amdgcn_mfma_f32_16x16x32_bf16(fH[0], cel0, aM, 0, 0, 0);
        aL = __builtin_amdgcn_mfma_f32_16x16x32_bf16(fL[0], ceh0, aL, 0, 0, 0);
        aH = __builtin_amdgcn_mfma_f32_16x16x32_bf16(fH[1], ceh1, aH, 0, 0, 0);
        aM = __builtin_amdgcn_mfma_f32_16x16x32_bf16(fH[1], cel1, aM, 0, 0, 0);
        aL = __builtin_amdgcn_mfma_f32_16x16x32_bf16(fL[1], ceh1, aL, 0, 0, 0);
        #pragma unroll
        for (int r = 0; r < 4; ++r) {
            float sv = (aH[r] + aM[r]) + aL[r];
            INS(m1[r], i1[r], m2[r], i2[r], m3[r], sv, kf);
        }

        if (t < 31) {
            // write tile t+1 into the OTHER buffer (readers fenced by the
            // previous iteration's end barrier; see R18).
            sbuf[(t & 1) ^ 1][tid] = nreg;
            if (t < 30) nreg = bfrag[(t + 2) * 256 + tid];
            __syncthreads();
        }
    }

    // cross-lane top-3 merge over the 16-lane code group
    #pragma unroll
    for (int r = 0; r < 4; ++r) {
        float M1 = m1[r], M2 = m2[r], M3 = m3[r];
        int   I1 = i1[r], I2 = i2[r];
        #pragma unroll
        for (int d = 1; d <= 8; d <<= 1) {
            float pm1 = __shfl_xor(M1, d, 64);
            int   pi1 = __shfl_xor(I1, d, 64);
            float pm2 = __shfl_xor(M2, d, 64);
            int   pi2 = __shfl_xor(I2, d, 64);
            float pm3 = __shfl_xor(M3, d, 64);
            INS(M1, I1, M2, I2, M3, pm1, pi1);
            INS(M1, I1, M2, I2, M3, pm2, pi2);
            M3 = fminf(M3, pm3);    // pm3 >= pm2 >= post-insert M2
        }
        m1[r] = M1; m2[r] = M2; m3[r] = M3;
        i1[r] = I1; i2[r] = I2;
    }

    if (lc == 0) {
        #pragma unroll
        for (int r = 0; r < 4; ++r) {
            int p  = wavePos + lg * 4 + r;
            bool g2 = (m2[r] - m1[r] <= DELTA);
            bool g3 = (m3[r] - m1[r] <= DELTA);
            if (!g2 && !g3) {
                out_idx[p] = (float)i1[r];     // PLAIN: final for the writer
            } else {
                int packed = i1[r] | (i2[r] << 9) | (1 << 18);
                if (g3) {
                    unsigned slot = atomicAdd(fullCnt, 1u);
                    if (slot < (unsigned)fullCap) {
                        fullList[slot] = (unsigned)p;
                        packed |= (1 << 19);   // listed g3: phase 2 resolves
                    } else {
                        packed |= (1 << 20);   // overflow: phase 1 full-scan
                    }
                }
                out_idx[p] = (float)packed;    // < 2^21: exact in fp32
            }
        }
    }
}

// ---------- resolve: merged res2 (phase 1) + wave-parallel g3 (phase 2) ---
// 2048 one-wave blocks. Phase 1: 1 position/thread sweep; fl==1 -> g2
// depth-2 resolve; bit20 -> serial full scan (overflow safety net, never
// executes); bit19 (listed g3) -> skip. Phase 2: grid-stride over g3 list,
// R12-proven wave-parallel exact scan (8 codes/lane). Disjoint positions.
__global__ __launch_bounds__(64) void vq_resolve(
        const float* __restrict__ in, const float* __restrict__ emb,
        const float* __restrict__ e2np, const unsigned* __restrict__ fullCnt,
        const unsigned* __restrict__ fullList, int fullCap,
        float* __restrict__ out_idx) {
    const int lane = threadIdx.x;

    // ---- phase 1: per-thread sweep (R18 res2 body) ----
    {
        const int n = blockIdx.x * 64 + lane;
        const int v = (int)out_idx[n];
        const int fl = v >> 18;
        if (fl && !(fl & 2)) {          // g2 or overflow (skip listed g3)
            const int b  = n >> 12;
            const int hw = n & (HWSZ - 1);
            const float* xp = in + ((size_t)b << 18) + hw;
            float x[EMB];
            #pragma unroll
            for (int c = 0; c < EMB; ++c) x[c] = xp[(size_t)c << 12];
            const float x2 = np_sumsq64(x);
            int kk;
            if (fl & 4) {
                // overflow safety net: exact full scan, first-min semantics
                float bu = 3.4e38f; int bk = 0;
                for (int k = 0; k < KCODE; ++k) {
                    float u = exact_u(x, x2, emb + k * EMB, e2np[k]);
                    if (u < bu) { bu = u; bk = k; }
                }
                kk = bk;
            } else {
                const int ia = v & 511, ib = (v >> 9) & 511;
                float u1 = exact_u(x, x2, emb + (size_t)ia * EMB, e2np[ia]);
                float u2 = exact_u(x, x2, emb + (size_t)ib * EMB, e2np[ib]);
                kk = (u1 < u2) ? ia : (u2 < u1 ? ib : (ia < ib ? ia : ib));
            }
            out_idx[n] = (float)kk;
        }
    }

    // ---- phase 2: listed g3, wave-parallel (R12 body) ----
    __shared__ float xbuf[EMB];
    unsigned cnt = *fullCnt;
    if (cnt > (unsigned)fullCap) cnt = (unsigned)fullCap;

    for (unsigned idx = blockIdx.x; idx < cnt; idx += gridDim.x) {
        const int n  = (int)fullList[idx];
        const int b  = n >> 12;
        const int hw = n & (HWSZ - 1);
        __syncthreads();   // single-wave block: cheap; fences xbuf reuse
        xbuf[lane] = in[((size_t)b << 18) + ((size_t)lane << 12) + hw];
        __syncthreads();

        float x2;
        {
            #pragma clang fp contract(off)
            float r0 = xbuf[0] * xbuf[0], r1 = xbuf[1] * xbuf[1];
            float r2 = xbuf[2] * xbuf[2], r3 = xbuf[3] * xbuf[3];
            float r4 = xbuf[4] * xbuf[4], r5 = xbuf[5] * xbuf[5];
            float r6 = xbuf[6] * xbuf[6], r7 = xbuf[7] * xbuf[7];
            #pragma unroll 1
            for (int i = 8; i < EMB; i += 8) {
                r0 += xbuf[i + 0] * xbuf[i + 0];
                r1 += xbuf[i + 1] * xbuf[i + 1];
                r2 += xbuf[i + 2] * xbuf[i + 2];
                r3 += xbuf[i + 3] * xbuf[i + 3];
                r4 += xbuf[i + 4] * xbuf[i + 4];
                r5 += xbuf[i + 5] * xbuf[i + 5];
                r6 += xbuf[i + 6] * xbuf[i + 6];
                r7 += xbuf[i + 7] * xbuf[i + 7];
            }
            x2 = ((r0 + r1) + (r2 + r3)) + ((r4 + r5) + (r6 + r7));
        }

        float bu = 3.4e38f;
        int   bk = 0x7fffffff;
        #pragma unroll 1
        for (int j = 0; j < 8; ++j) {
            const int k = j * 64 + lane;
            const float* ek = emb + (size_t)k * EMB;
            float t0 = 0.f, t1 = 0.f, t2 = 0.f, t3 = 0.f;
            #pragma unroll 4
            for (int c = 0; c < EMB; c += 4) {
                t0 = fmaf(xbuf[c + 0], ek[c + 0], t0);
                t1 = fmaf(xbuf[c + 1], ek[c + 1], t1);
                t2 = fmaf(xbuf[c + 2], ek[c + 2], t2);
                t3 = fmaf(xbuf[c + 3], ek[c + 3], t3);
            }
            float xe  = (t0 + t1) + (t2 + t3);
            float tmp = x2 - 2.0f * xe;
            float u   = tmp + e2np[k];
            if (u < bu || (u == bu && k < bk)) { bu = u; bk = k; }
        }
        #pragma unroll
        for (int d = 1; d < 64; d <<= 1) {
            float ou = __shfl_xor(bu, d, 64);
            int   ok = __shfl_xor(bk, d, 64);
            if (ou < bu || (ou == bu && ok < bk)) { bu = ou; bk = ok; }
        }
        if (lane == 0) out_idx[n] = (float)bk;   // plain index, flags cleared
    }
}

// ---------- writer: float4-along-hw, 4 positions x 16 dims per thread -----
// quarter = g>>15: all 64 lanes of a wave share the dim-plane -> every
// load/store is 64 lanes x 16B = 1KB contiguous. 49 VMEM/thread.
__global__ __launch_bounds__(256) void vq_write(
        const float* __restrict__ in, const float* __restrict__ emb,
        const float* __restrict__ out_idx, float* __restrict__ out_q,
        float* __restrict__ partials,           // ws+8, [512]
        unsigned* __restrict__ ticket,          // ws+1
        float* __restrict__ out_loss) {
    const int tid  = threadIdx.x;
    const int wave = tid >> 6;
    const int lane = tid & 63;
    const int g    = blockIdx.x * 256 + tid;    // 0..131071
    const int pg   = g & 32767;                 // position group (4 pos)
    const int qt   = g >> 15;                   // dim quarter (0..3)
    const int p0   = pg << 2;
    const int b    = p0 >> 12;
    const int hw0  = p0 & (HWSZ - 1);
    const int d0   = qt << 4;

    // 4 plain indices (contract: screen/resolve finished all resolution)
    float4 vi = *(const float4*)(out_idx + p0);
    const int k0 = (int)vi.x, k1 = (int)vi.y, k2 = (int)vi.z, k3 = (int)vi.w;
    const float* e0 = emb + (size_t)k0 * EMB + d0;
    const float* e1 = emb + (size_t)k1 * EMB + d0;
    const float* e2 = emb + (size_t)k2 * EMB + d0;
    const float* e3 = emb + (size_t)k3 * EMB + d0;

    const size_t base = ((size_t)b << 18) + ((size_t)d0 << 12) + hw0;
    const float* xp = in    + base;
    float*       op = out_q + base;

    float s = 0.0f;
    #pragma unroll
    for (int j = 0; j < 4; ++j) {               // 4-dim group: d = d0+4j..+3
        float4 q0 = *(const float4*)(e0 + 4 * j);   // position-major gathers
        float4 q1 = *(const float4*)(e1 + 4 * j);
        float4 q2 = *(const float4*)(e2 + 4 * j);
        float4 q3 = *(const float4*)(e3 + 4 * j);
        // dim-major x loads / stores (contiguous along hw)
        #pragma unroll
        for (int dd = 0; dd < 4; ++dd) {
            const size_t off = ((size_t)(4 * j + dd) << 12);
            float4 xv = *(const float4*)(xp + off);
            float4 ov;
            ov.x = dd == 0 ? q0.x : dd == 1 ? q0.y : dd == 2 ? q0.z : q0.w;
            ov.y = dd == 0 ? q1.x : dd == 1 ? q1.y : dd == 2 ? q1.z : q1.w;
            ov.z = dd == 0 ? q2.x : dd == 1 ? q2.y : dd == 2 ? q2.z : q2.w;
            ov.w = dd == 0 ? q3.x : dd == 1 ? q3.y : dd == 2 ? q3.z : q3.w;
            float u0 = ov.x - xv.x, u1 = ov.y - xv.y;
            float u2 = ov.z - xv.z, u3 = ov.w - xv.w;
            s = fmaf(u0, u0, s); s = fmaf(u1, u1, s);
            s = fmaf(u2, u2, s); s = fmaf(u3, u3, s);
            *(float4*)(op + off) = ov;
        }
    }

    // loss: wave shuffle -> LDS -> block partial -> last-block ticket
    #pragma unroll
    for (int off = 32; off > 0; off >>= 1)
        s += __shfl_down(s, off, 64);
    __shared__ float red[4];
    if (lane == 0) red[wave] = s;
    __syncthreads();
    if (tid == 0) {
        partials[blockIdx.x] = (red[0] + red[1]) + (red[2] + red[3]);
        __threadfence();
        unsigned tk = atomicAdd(ticket, 1u);
        if (tk == 511u) {
            __threadfence();
            float a0 = 0.f, a1 = 0.f, a2 = 0.f, a3 = 0.f;
            float a4 = 0.f, a5 = 0.f, a6 = 0.f, a7 = 0.f;
            for (int i = 0; i < 512; i += 8) {
                a0 += partials[i + 0]; a1 += partials[i + 1];
                a2 += partials[i + 2]; a3 += partials[i + 3];
                a4 += partials[i + 4]; a5 += partials[i + 5];
                a6 += partials[i + 6]; a7 += partials[i + 7];
            }
            float tot = ((a0 + a1) + (a2 + a3)) + ((a4 + a5) + (a6 + a7));
            out_loss[0] = 1.25f * tot * (1.0f / ((float)NPOS * (float)EMB));
        }
    }
}

extern "C" void kernel_launch(void* const* d_in, const int* in_sizes, int n_in,
                              void* d_out, int out_size, void* d_ws, size_t ws_size,
                              hipStream_t stream) {
    const float* in  = (const float*)d_in[0];
    const float* emb = (const float*)d_in[1];
    float* ws  = (float*)d_ws;
    float* out = (float*)d_out;

    float*    out_loss = out;
    float*    out_q    = out + 1;
    float*    out_idx  = out + 1 + (size_t)NPOS * EMB;
    unsigned* fullCnt  = (unsigned*)ws;          // ws[0]
    unsigned* ticket   = (unsigned*)ws + 1;      // ws[1]
    float*    partials = ws + 8;                 // [512]
    float*    e2np     = ws + 1032;              // [512]
    short8*   bfrag    = (short8*)(ws + 1544);   // 128 KB
    unsigned* fullList = (unsigned*)(ws + 34312);

    // g3 list capacity limited by what the workspace provably holds;
    // shrinkage only triggers the (correct) overflow path in resolve.
    long avail = (long)(ws_size / 4) - 34312;
    int  fullCap = avail > 0 ? (avail > 1024 ? 1024 : (int)avail) : 0;

    vq_prep<<<16, 256, 0, stream>>>(emb, ws);
    vq_screen<<<NPOS / 64, 256, 0, stream>>>(in, e2np, bfrag, out_idx,
                                             fullCnt, fullList, fullCap);
    vq_resolve<<<2048, 64, 0, stream>>>(in, emb, e2np, fullCnt, fullList,
                                        fullCap, out_idx);
    vq_write<<<NPOS / 256, 256, 0, stream>>>(in, emb, out_idx, out_q,
                                             partials, ticket, out_loss);
}